// Round 1
// baseline (339.753 us; speedup 1.0000x reference)
//
#include <hip/hip_runtime.h>
#include <hip/hip_bf16.h>

// Problem constants (fixed in the reference file)
constexpr int B_MAX  = 8;
constexpr int S      = 512;
constexpr int D      = 768;
constexpr int H_IMG  = 1024;
constexpr int W_IMG  = 768;
constexpr int STRIDE = 8;
constexpr int R  = H_IMG / STRIDE;   // 128
constexpr int C  = W_IMG / STRIDE;   // 96
constexpr int RC = R * C;            // 12288

// ---------------------------------------------------------------------------
// Phase 1: per-batch segmentation. One block of S threads per batch.
// Computes: word start token, word token count, word box (already /stride),
// number of words.
// ---------------------------------------------------------------------------
__global__ void seg_kernel(const int* __restrict__ coors,
                           const int* __restrict__ mask,
                           const int* __restrict__ stride_ptr,
                           int* __restrict__ wstart,
                           int* __restrict__ wcnt,
                           int* __restrict__ wbox,
                           int* __restrict__ nwords_arr) {
    const int b = blockIdx.x;
    const int t = threadIdx.x;

    __shared__ int s_nvalid;
    __shared__ int scan[S];
    __shared__ int sstart[S];

    if (t == 0) s_nvalid = S;
    __syncthreads();
    if (mask[b * S + t] == 0) atomicMin(&s_nvalid, t);
    __syncthreads();
    const int nv = s_nvalid;               // tokens [0, nv) are valid
    const bool valid = t < nv;

    const int4 c4 = *(const int4*)(coors + (size_t)(b * S + t) * 4);
    bool same = false;
    if (t > 0) {
        const int4 p4 = *(const int4*)(coors + (size_t)(b * S + t - 1) * 4);
        same = (c4.x == p4.x) && (c4.y == p4.y) && (c4.z == p4.z) && (c4.w == p4.w);
    }
    const int nw = (valid && (t == 0 || !same)) ? 1 : 0;

    scan[t] = nw;
    __syncthreads();
    // Hillis-Steele inclusive scan over S=512
    for (int off = 1; off < S; off <<= 1) {
        int v = scan[t] + ((t >= off) ? scan[t - off] : 0);
        __syncthreads();
        scan[t] = v;
        __syncthreads();
    }

    const int stride = *stride_ptr;
    if (nw) {
        const int w = scan[t] - 1;         // this token starts word w
        sstart[w] = t;
        int* bx = wbox + ((size_t)b * S + w) * 4;
        bx[0] = c4.y / stride;             // r0
        bx[1] = c4.w / stride;             // r1
        bx[2] = c4.x / stride;             // c0
        bx[3] = c4.z / stride;             // c1
    }
    __syncthreads();

    const int NW = scan[S - 1];            // total words (flat after nv)
    if (t == 0) nwords_arr[b] = NW;
    if (t < NW) {
        const int st  = sstart[t];
        const int nxt = (t + 1 < NW) ? sstart[t + 1] : nv;
        wstart[b * S + t] = st;
        wcnt[b * S + t]   = nxt - st;
    }
}

// ---------------------------------------------------------------------------
// Phase 2: valw[b][w][:] = mean of embeddings of word (w-1); zeros for w==0.
// One block per (b, w).
// ---------------------------------------------------------------------------
__global__ void mean_kernel(const float* __restrict__ emb,
                            const int* __restrict__ wstart,
                            const int* __restrict__ wcnt,
                            const int* __restrict__ nwords_arr,
                            float* __restrict__ valw) {
    const int bw = blockIdx.x;
    const int b  = bw / S;
    const int w  = bw % S;
    if (w >= nwords_arr[b]) return;

    float* out = valw + ((size_t)b * S + w) * D;
    if (w == 0) {
        for (int d = threadIdx.x; d < D; d += blockDim.x) out[d] = 0.0f;
        return;
    }
    const int pst  = wstart[b * S + w - 1];
    const int pcnt = wcnt[b * S + w - 1];
    const float inv = 1.0f / (float)max(pcnt, 1);
    const float* e0 = emb + ((size_t)b * S + pst) * D;
    for (int d = threadIdx.x; d < D; d += blockDim.x) {
        float s = 0.0f;
        for (int k = 0; k < pcnt; ++k) s += e0[(size_t)k * D + d];
        out[d] = s * inv;
    }
}

// ---------------------------------------------------------------------------
// Phase 3: last-writer paint. last[b][r][c] = max word index covering pixel.
// ---------------------------------------------------------------------------
__global__ void init_last(int* __restrict__ last, int n) {
    int i = blockIdx.x * blockDim.x + threadIdx.x;
    if (i < n) last[i] = -1;
}

__global__ void paint_kernel(const int* __restrict__ wbox,
                             const int* __restrict__ nwords_arr,
                             int* __restrict__ last) {
    const int b = blockIdx.y;
    const int w = blockIdx.x;
    if (w >= nwords_arr[b]) return;
    const int* bx = wbox + ((size_t)b * S + w) * 4;
    const int r0 = max(bx[0], 0), r1 = min(bx[1], R);
    const int c0 = max(bx[2], 0), c1 = min(bx[3], C);
    const int nr = r1 - r0, nc = c1 - c0;
    if (nr <= 0 || nc <= 0) return;
    const int tot = nr * nc;
    for (int i = threadIdx.x; i < tot; i += blockDim.x) {
        const int r = r0 + i / nc;
        const int c = c0 + i % nc;
        atomicMax(&last[b * RC + r * C + c], w);
    }
}

// ---------------------------------------------------------------------------
// Phase 4: scatter the word means into the grid. Coalesced float4 writes
// along the pixel dimension; `last` and `valw` are L2-resident.
// out[((b*D + d)*RC) + rc] = last[b][rc] >= 0 ? valw[b][last][d] : 0
// ---------------------------------------------------------------------------
__global__ void out_kernel(const float* __restrict__ valw,
                           const int* __restrict__ last,
                           float* __restrict__ out,
                           int Bv) {
    const size_t i = (size_t)blockIdx.x * blockDim.x + threadIdx.x;
    const size_t total = (size_t)Bv * D * (RC / 4);
    if (i >= total) return;
    const int    rc4 = (int)(i % (RC / 4));
    const size_t bd  = i / (RC / 4);
    const int    d   = (int)(bd % D);
    const int    b   = (int)(bd / D);

    const int4 l4 = ((const int4*)(last + (size_t)b * RC))[rc4];
    const float* vb = valw + (size_t)b * S * D + d;
    float4 o;
    o.x = (l4.x >= 0) ? vb[(size_t)l4.x * D] : 0.0f;
    o.y = (l4.y >= 0) ? vb[(size_t)l4.y * D] : 0.0f;
    o.z = (l4.z >= 0) ? vb[(size_t)l4.z * D] : 0.0f;
    o.w = (l4.w >= 0) ? vb[(size_t)l4.w * D] : 0.0f;
    ((float4*)out)[i] = o;
}

// ---------------------------------------------------------------------------
extern "C" void kernel_launch(void* const* d_in, const int* in_sizes, int n_in,
                              void* d_out, int out_size, void* d_ws, size_t ws_size,
                              hipStream_t stream) {
    const float* emb        = (const float*)d_in[0];
    const int*   coors      = (const int*)d_in[1];
    const int*   mask       = (const int*)d_in[2];
    const int*   stride_ptr = (const int*)d_in[5];
    float*       out        = (float*)d_out;

    const int Bv = in_sizes[2] / S;   // 8

    // Workspace layout (all re-initialized every call; ws is poisoned 0xAA)
    float* valw   = (float*)d_ws;                       // Bv*S*D floats
    int*   last   = (int*)(valw + (size_t)Bv * S * D);  // Bv*RC ints
    int*   wstart = last + (size_t)Bv * RC;             // Bv*S
    int*   wcnt   = wstart + (size_t)Bv * S;            // Bv*S
    int*   wbox   = wcnt + (size_t)Bv * S;              // Bv*S*4
    int*   nwords = wbox + (size_t)Bv * S * 4;          // Bv

    seg_kernel<<<Bv, S, 0, stream>>>(coors, mask, stride_ptr, wstart, wcnt, wbox, nwords);
    mean_kernel<<<Bv * S, 256, 0, stream>>>(emb, wstart, wcnt, nwords, valw);
    init_last<<<(Bv * RC + 255) / 256, 256, 0, stream>>>(last, Bv * RC);
    paint_kernel<<<dim3(S, Bv), 64, 0, stream>>>(wbox, nwords, last);

    const size_t total = (size_t)Bv * D * (RC / 4);
    out_kernel<<<(unsigned)((total + 255) / 256), 256, 0, stream>>>(valw, last, out, Bv);
}